// Round 24
// baseline (281.569 us; speedup 1.0000x reference)
//
#include <hip/hip_runtime.h>
#include <cstdint>
#include <cstddef>

// ---------------- constants ----------------
constexpr int T_SEQ = 4096;
constexpr int NH    = 16;
constexpr int HD    = 128;
constexpr int DIM   = 2048;
constexpr int HDIM  = 2048;   // NH*HD

typedef __attribute__((ext_vector_type(8)))  short  short8;
typedef __attribute__((ext_vector_type(4)))  float  f32x4;
typedef __attribute__((ext_vector_type(16))) float  f32x16;
typedef __attribute__((ext_vector_type(8)))  unsigned short u16x8;
typedef __attribute__((ext_vector_type(4)))  unsigned short u16x4;
typedef __attribute__((ext_vector_type(4)))  unsigned uint4v;
typedef __attribute__((ext_vector_type(2)))  int int2v;

__device__ __forceinline__ unsigned short f2bf(float f) {
  unsigned u = __float_as_uint(f);
  return (unsigned short)((u + 0x7FFFu + ((u >> 16) & 1u)) >> 16);  // RNE
}
__device__ __forceinline__ float bf2f(unsigned short h) {
  return __uint_as_float(((unsigned)h) << 16);
}
__device__ __forceinline__ void gload_lds16(const void* g, void* l) {
  __builtin_amdgcn_global_load_lds((const __attribute__((address_space(1))) void*)g,
                                   (__attribute__((address_space(3))) void*)l, 16, 0, 0);
}
__device__ __forceinline__ int2v plswap(int a, int b) {
  return __builtin_amdgcn_permlane32_swap(a, b, false, false);
}
__device__ __forceinline__ void bar() {           // raw barrier: no implicit vmcnt(0)
  asm volatile("" ::: "memory");
  __builtin_amdgcn_s_barrier();
  asm volatile("" ::: "memory");
}
#define VMCNT(n) asm volatile("s_waitcnt vmcnt(" #n ")" ::: "memory")

// ---------------- fused prep: 3x fp32->bf16 convert + RoPE tables, one launch ----------
__global__ __launch_bounds__(256) void prep_all(const float* __restrict__ x,
                                                const float* __restrict__ qkv_w,
                                                const float* __restrict__ proj_w,
                                                unsigned short* __restrict__ xb,
                                                unsigned short* __restrict__ wqb,
                                                unsigned short* __restrict__ pwb,
                                                float* __restrict__ cosT,
                                                float* __restrict__ sinT) {
  constexpr int N1 = T_SEQ * DIM / 4;              // 2,097,152
  constexpr int N2 = N1 + 3 * HDIM * DIM / 4;      // +3,145,728
  constexpr int N3 = N2 + DIM * HDIM / 4;          // +1,048,576
  int gid = blockIdx.x * 256 + threadIdx.x;
  const float* src; unsigned short* dst; int i4;
  if (gid < N1)      { src = x;      dst = xb;  i4 = gid; }
  else if (gid < N2) { src = qkv_w;  dst = wqb; i4 = gid - N1; }
  else if (gid < N3) { src = proj_w; dst = pwb; i4 = gid - N2; }
  else {
    int idx = gid - N3;                            // T_SEQ*64 entries
    int t = idx >> 6, i = idx & 63;
    float ang = (i < 32) ? exp2f(-10.0f * (float)i / 31.0f) : 0.0f;  // (1/1024)^(i/31)
    float th = (float)t * ang;
    cosT[idx] = cosf(th);
    sinT[idx] = sinf(th);
    return;
  }
  float4 v = ((const float4*)src)[i4];
  u16x4 o; o.x = f2bf(v.x); o.y = f2bf(v.y); o.z = f2bf(v.z); o.w = f2bf(v.w);
  ((u16x4*)dst)[i4] = o;
}

// ---------------- GEMM: C = A * B^T (deep-pipelined, T2+T3+T4+T5) ----------------
// Barrier-minimal K-loop (R16, best measured): only 2 load-bearing barriers/K-tile.
template <int MODE>
__global__ __launch_bounds__(512) void gemm256(const unsigned short* __restrict__ A,
                                               const unsigned short* __restrict__ B,
                                               int K, unsigned short* __restrict__ outb,
                                               float* __restrict__ outf, int N) {
  __shared__ __align__(16) char SM[3 * 49152];   // 144KB: 3 x [A 16KB | B 32KB]
  const int tid = threadIdx.x, w = tid >> 6, lane = tid & 63;
  const int wm = w >> 2, wn = w & 3;
  const int lr = lane >> 4, lc = lane & 15, lc7 = lc & 7;
  const int cpx = gridDim.x >> 3;
  const int idx = (blockIdx.x & 7) * cpx + (blockIdx.x >> 3);
  const int m0 = (idx & 31) * 128, n0 = (idx >> 5) * 256;

  const int arow = lane >> 3;
  const int xcol = ((lane & 7) ^ ((lane >> 3) & 7)) * 8;  // pre-swizzled source col

  auto stageA = [&](int buf, int t) {
    char* base = SM + buf * 49152;
#pragma unroll
    for (int i = 0; i < 2; i++) {
      int c = w + i * 8;
      gload_lds16(A + (size_t)(m0 + c * 8 + arow) * K + t * 64 + xcol, base + c * 1024);
    }
  };
  auto stageB0 = [&](int buf, int t) {
    char* base = SM + buf * 49152 + 16384;
    gload_lds16(B + (size_t)(n0 + w * 8 + arow) * K + t * 64 + xcol, base + w * 1024);
  };
  auto stageB1 = [&](int buf, int t) {
    char* base = SM + buf * 49152 + 16384;
#pragma unroll
    for (int i = 1; i < 4; i++) {
      int c = w + i * 8;
      gload_lds16(B + (size_t)(n0 + c * 8 + arow) * K + t * 64 + xcol, base + c * 1024);
    }
  };

  f32x4 acc[4][4] = {};
  const int NT = K >> 6;

  stageA(0, 0); stageB0(0, 0); stageB1(0, 0);
  stageA(1, 1); stageB0(1, 1); stageB1(1, 1);
  VMCNT(6);
  bar();

#pragma unroll 1
  for (int t = 0; t < NT; t++) {
    const int c = t % 3, s = (t + 2) % 3;
    const bool st = (t + 2) < NT;
    const char* Ab = SM + c * 49152;
    const char* Bb = Ab + 16384;

    short8 a[4], b[4];
#pragma unroll
    for (int mi = 0; mi < 4; mi++)
      a[mi] = *(const short8*)(Ab + (wm * 64 + mi * 16 + lc) * 128 + ((0 + lr) ^ lc7) * 16);
#pragma unroll
    for (int ni = 0; ni < 4; ni++)
      b[ni] = *(const short8*)(Bb + (wn * 64 + ni * 16 + lc) * 128 + ((0 + lr) ^ lc7) * 16);
    if (st) { stageA(s, t + 2); stageB0(s, t + 2); }
    __builtin_amdgcn_s_setprio(1);
#pragma unroll
    for (int mi = 0; mi < 4; mi++)
#pragma unroll
      for (int ni = 0; ni < 4; ni++)
        acc[mi][ni] = __builtin_amdgcn_mfma_f32_16x16x32_bf16(a[mi], b[ni], acc[mi][ni], 0, 0, 0);
    __builtin_amdgcn_s_setprio(0);

#pragma unroll
    for (int mi = 0; mi < 4; mi++)
      a[mi] = *(const short8*)(Ab + (wm * 64 + mi * 16 + lc) * 128 + ((4 + lr) ^ lc7) * 16);
#pragma unroll
    for (int ni = 0; ni < 4; ni++)
      b[ni] = *(const short8*)(Bb + (wn * 64 + ni * 16 + lc) * 128 + ((4 + lr) ^ lc7) * 16);
    if (st) stageB1(s, t + 2);
    if (st) { VMCNT(6); } else { VMCNT(0); }   // confirm tile t+1 (tail: drain)
    bar();                                     // (a) all waves' t+1 staging landed
    __builtin_amdgcn_s_setprio(1);
#pragma unroll
    for (int mi = 0; mi < 4; mi++)
#pragma unroll
      for (int ni = 0; ni < 4; ni++)
        acc[mi][ni] = __builtin_amdgcn_mfma_f32_16x16x32_bf16(a[mi], b[ni], acc[mi][ni], 0, 0, 0);
    __builtin_amdgcn_s_setprio(0);
    bar();                                     // (b) protect buf c vs t+1's stage
  }

#pragma unroll
  for (int mi = 0; mi < 4; mi++)
#pragma unroll
    for (int ni = 0; ni < 4; ni++)
#pragma unroll
      for (int r = 0; r < 4; r++) {
        int t = m0 + wm * 64 + mi * 16 + lr * 4 + r;
        int n = n0 + wn * 64 + ni * 16 + lc;
        float v = acc[mi][ni][r];
        if (MODE == 0) {
          int cc = n >> 11, e = n & 2047, h = e >> 7, d = e & 127;
          outb[(((size_t)cc * NH + h) * T_SEQ + t) * HD + d] = f2bf(v);
        } else {
          outf[(size_t)t * N + n] = v;
        }
      }
}

// ------- fused RMSNorm+RoPE (q,k -> FP8 e4m3) + vmix-transpose (v) -------
__global__ __launch_bounds__(256) void norm_vmix(const unsigned short* __restrict__ qkvb,
                                                 const float* __restrict__ cosT,
                                                 const float* __restrict__ sinT,
                                                 const float* __restrict__ ve,
                                                 const float* __restrict__ lam,
                                                 unsigned short* __restrict__ vt,
                                                 unsigned char* __restrict__ qk8) {
  __shared__ float tile[64][65];
  const int bid = blockIdx.x, tid = threadIdx.x;

  if (bid < 8192) {
    const int li = tid & 15;                        // position within row (8 elems each)
    const int row = bid * 16 + (tid >> 4);          // row over [c][h][t], c in {0,1}
    const int t = row & (T_SEQ - 1);
    const unsigned short* rp = qkvb + (size_t)row * HD + li * 8;
    u16x8 raw = *(const u16x8*)rp;

    float v[8]; float ss = 0.0f;
#pragma unroll
    for (int j = 0; j < 8; j++) { v[j] = bf2f(raw[j]); ss += v[j] * v[j]; }
#pragma unroll
    for (int off = 1; off < 16; off <<= 1) ss += __shfl_xor(ss, off, 16);
    float rs = rsqrtf(ss * (1.0f / 128.0f) + 1e-6f);
    if (row < NH * T_SEQ) rs *= 0.088388347648318447f * 1.44269504f;  // q rows only

    uint4v rw = __builtin_bit_cast(uint4v, raw);
    uint4v pwv;
    pwv.x = (unsigned)__shfl_xor((int)rw.x, 8, 16);
    pwv.y = (unsigned)__shfl_xor((int)rw.y, 8, 16);
    pwv.z = (unsigned)__shfl_xor((int)rw.z, 8, 16);
    pwv.w = (unsigned)__shfl_xor((int)rw.w, 8, 16);
    u16x8 praw = __builtin_bit_cast(u16x8, pwv);
    float pv[8];
#pragma unroll
    for (int j = 0; j < 8; j++) pv[j] = bf2f(praw[j]);

    const int e0 = (li & 7) * 8;
    const bool hi8 = li >= 8;
    float4 c0 = *(const float4*)(cosT + t * 64 + e0);
    float4 c1 = *(const float4*)(cosT + t * 64 + e0 + 4);
    float4 s0 = *(const float4*)(sinT + t * 64 + e0);
    float4 s1 = *(const float4*)(sinT + t * 64 + e0 + 4);
    float cc[8] = {c0.x, c0.y, c0.z, c0.w, c1.x, c1.y, c1.z, c1.w};
    float sn[8] = {s0.x, s0.y, s0.z, s0.w, s1.x, s1.y, s1.z, s1.w};

    float rr[8];
#pragma unroll
    for (int j = 0; j < 8; j++) {
      float x1 = hi8 ? pv[j] : v[j];
      float x2 = hi8 ? v[j] : pv[j];
      float r = hi8 ? (-x1 * sn[j] + x2 * cc[j]) : (x1 * cc[j] + x2 * sn[j]);
      rr[j] = r * rs;
    }
    int w0 = 0, w1 = 0;
    w0 = __builtin_amdgcn_cvt_pk_fp8_f32(rr[0], rr[1], w0, false);
    w0 = __builtin_amdgcn_cvt_pk_fp8_f32(rr[2], rr[3], w0, true);
    w1 = __builtin_amdgcn_cvt_pk_fp8_f32(rr[4], rr[5], w1, false);
    w1 = __builtin_amdgcn_cvt_pk_fp8_f32(rr[6], rr[7], w1, true);
    int2v o8; o8.x = w0; o8.y = w1;
    *(int2v*)(qk8 + (size_t)row * HD + li * 8) = o8;
  } else {
    const int j2 = bid - 8192;                      // 0..2047
    const int t0 = (j2 & 63) * 64, d0 = ((j2 >> 6) & 1) * 64, h = j2 >> 7;
    const unsigned short* vb = qkvb + (size_t)2 * NH * T_SEQ * HD;
    const float l0 = lam[0], l1 = lam[1];
    const int tl = tid >> 4, dl4 = (tid & 15) * 4;
#pragma unroll
    for (int i = 0; i < 4; i++) {
      int t_local = tl + i * 16;
      int t = t0 + t_local;
      const unsigned short* vp = vb + ((size_t)h * T_SEQ + t) * HD + d0 + dl4;
      const float* vep = ve + (size_t)t * HDIM + h * HD + d0 + dl4;
      u16x4 vv = *(const u16x4*)vp;
      float4 vef = *(const float4*)vep;
      tile[t_local][dl4 + 0] = l0 * bf2f(vv.x) + l1 * vef.x;
      tile[t_local][dl4 + 1] = l0 * bf2f(vv.y) + l1 * vef.y;
      tile[t_local][dl4 + 2] = l0 * bf2f(vv.z) + l1 * vef.z;
      tile[t_local][dl4 + 3] = l0 * bf2f(vv.w) + l1 * vef.w;
    }
    __syncthreads();
#pragma unroll
    for (int i = 0; i < 2; i++) {
      int idx = tid + i * 256;
      int d_local = idx >> 3, tloc = (idx & 7) * 8;
      u16x8 o;
#pragma unroll
      for (int j = 0; j < 8; j++) o[j] = f2bf(tile[tloc + j][d_local]);
      *(u16x8*)(vt + ((size_t)h * HD + d0 + d_local) * T_SEQ + t0 + tloc) = o;
    }
  }
}

// ---------------- flash attention (causal): FP8 QK^T + bf16 PV, 32x32x16 ----------------
// R20/R22 best measured (118us): fp8 QK (K LDS tile 8KB), FM=18.75, sigma K-row
// permutation (lane-local PV), kv-parity group split with drift barriers, double-
// buffered K+V, bf16 output.
__global__ __launch_bounds__(512)
__attribute__((amdgpu_waves_per_eu(2, 2)))
void attn_fwd(const unsigned char* __restrict__ q8,
              const unsigned char* __restrict__ k8,
              const unsigned short* __restrict__ vt,
              unsigned short* __restrict__ ao) {
  __shared__ __align__(16) char SMEM[98304];    // [group][ K 2x8KB | V 2x16KB ]
  __shared__ int gctr[2];                       // group-barrier monotonic counters
  const int bid = blockIdx.x;
  const int h  = (bid & 7) + ((bid >> 7) << 3);  // XCD swizzle: head h on XCD h%8
  const int pr = (bid >> 3) & 15;
  const int tid = threadIdx.x, w = tid >> 6, lane = tid & 63;
  const int g = w >> 2, wq = w & 3;
  const int l31 = lane & 31, hi = lane >> 5, r7 = l31 & 7;
  const unsigned char* qh = q8 + (size_t)h * T_SEQ * HD;
  const unsigned char* kh = k8 + (size_t)h * T_SEQ * HD;
  const unsigned short* vh = vt + (size_t)h * HD * T_SEQ;

  if (tid < 2) gctr[tid] = 0;
  __syncthreads();
  int bcnt = 0;
  auto GBAR = [&]() {   // group-local barrier: 4 waves of group g
    asm volatile("s_waitcnt lgkmcnt(0)" ::: "memory");
    ++bcnt;
    if (lane == 0)
      __hip_atomic_fetch_add(&gctr[g], 1, __ATOMIC_RELEASE, __HIP_MEMORY_SCOPE_WORKGROUP);
    while (__hip_atomic_load(&gctr[g], __ATOMIC_ACQUIRE, __HIP_MEMORY_SCOPE_WORKGROUP) < 4 * bcnt)
      __builtin_amdgcn_s_sleep(1);
  };

  char* Kbase = SMEM + g * 49152;               // 2 x 8KB
  char* Vbase = Kbase + 16384;                  // 2 x 16KB

  const int vcrow = lane >> 3, vslot0 = lane & 7;    // V staging: 8 rows / 1KB chunk

  auto STAGE = [&](int buf, int t) {                 // t = global kv tile index
#pragma unroll
    for (int i = 0; i < 2; i++) {
      int c = wq * 2 + i;
      int r = c * 8 + (lane >> 3);                   // LDS row position
      int rsrc = (r & ~12) | ((r & 4) << 1) | ((r & 8) >> 1);  // sigma: b2<->b3
      int sl = ((lane & 7) ^ (r & 7)) * 16;          // pre-swizzled source slot
      gload_lds16(kh + (size_t)(t * 64 + rsrc) * HD + sl,
                  Kbase + buf * 8192 + c * 1024);
    }
#pragma unroll
    for (int i = 0; i < 4; i++) {
      int vrow = (wq * 4 + i) * 8 + vcrow;
      int vcol = (vslot0 ^ (vrow & 7)) * 8;
      gload_lds16(vh + (size_t)vrow * T_SEQ + t * 64 + vcol,
                  Vbase + buf * 16384 + (wq * 4 + i) * 1024);
    }
  };

  const float FM = 18.75f;   // fixed softmax max (exp2 domain) incl. fp8 norm inflation

#pragma unroll 1
  for (int which = 0; which < 2; ++which) {
    const int qt = which ? pr : (31 - pr);     // heavy tile first
    const int ng = qt + 1;                     // tiles for THIS group (parity g)
    const int q_row = qt * 128 + wq * 32 + l31;

    long qf8[8];                               // B-frag: Q[q_row][16dk + 8hi + 0..7] fp8
#pragma unroll
    for (int dk = 0; dk < 8; dk++)
      qf8[dk] = *(const long*)(qh + (size_t)q_row * HD + dk * 16 + hi * 8);

    f32x16 accO[4] = {};                       // O^T: col=q, rows d (4 tiles of 32)
    float l_r = 0.0f;

    __syncthreads();                           // prev combine reads done (cross-group)
    STAGE(0, g);

#pragma unroll 1
    for (int it = 0; it < ng; it++) {
      const int t = 2 * it + g;                // this group's kv tile
      const int cur = it & 1;
      asm volatile("s_waitcnt vmcnt(0)" ::: "memory");  // own stage(cur) landed
      GBAR();                                           // group's stage(cur) landed
      if (it + 1 < ng) STAGE(cur ^ 1, t + 2);           // prefetch under compute

      // ---- S^T = K Q^T : 2 kv-subtiles x 8 d-steps (fp8 x fp8 -> f32) ----
      f32x16 accS0 = {}, accS1 = {};
      const char* Kb = Kbase + cur * 8192;
      __builtin_amdgcn_s_setprio(1);
#pragma unroll
      for (int dk = 0; dk < 8; dk++) {
        int off = l31 * 128 + ((dk ^ r7) * 16) + hi * 8;
        long k0 = *(const long*)(Kb + off);
        long k1 = *(const long*)(Kb + 32 * 128 + off);
        accS0 = __builtin_amdgcn_mfma_f32_32x32x16_fp8_fp8(k0, qf8[dk], accS0, 0, 0, 0);
        accS1 = __builtin_amdgcn_mfma_f32_32x32x16_fp8_fp8(k1, qf8[dk], accS1, 0, 0, 0);
      }
      __builtin_amdgcn_s_setprio(0);

      // ---- causal mask + exp2(s - FM); permuted layout: kv = 64t+(r&7)+8hi+16(r>>3) ----
      float p[32];
      const bool need_mask = (t * 64 + 63) > (qt * 128 + wq * 32);
      if (need_mask) {
#pragma unroll
        for (int r = 0; r < 16; r++) {
          int kv0 = t * 64 + (r & 7) + 8 * hi + 16 * (r >> 3);
          p[r]      = (kv0      > q_row) ? 0.0f : exp2f(accS0[r] - FM);
          p[16 + r] = (kv0 + 32 > q_row) ? 0.0f : exp2f(accS1[r] - FM);
        }
      } else {
#pragma unroll
        for (int r = 0; r < 16; r++) {
          p[r]      = exp2f(accS0[r] - FM);
          p[16 + r] = exp2f(accS1[r] - FM);
        }
      }

      // ---- row sum (partner holds complementary kv set; one cross-half swap) ----
      float s16[16];
#pragma unroll
      for (int i = 0; i < 16; i++) s16[i] = p[i] + p[i + 16];
#pragma unroll
      for (int st = 8; st >= 1; st >>= 1)
#pragma unroll
        for (int i = 0; i < st; i++) s16[i] += s16[i + st];
      int2v sr_ = plswap(__float_as_int(s16[0]), __float_as_int(s16[0]));
      l_r += s16[0] + __int_as_float(hi ? sr_.x : sr_.y);

      // ---- PV: O^T += V^T P^T ; pb[ks] = p[8ks..8ks+7] (lane-local, no exchange) ----
      const char* Vb = Vbase + cur * 16384 + l31 * 128;
#pragma unroll
      for (int ks = 0; ks < 4; ks++) {
        uint4v pw;
#pragma unroll
        for (int w2 = 0; w2 < 4; w2++) {
          unsigned pk_;
          asm("v_cvt_pk_bf16_f32 %0, %1, %2"
              : "=v"(pk_) : "v"(p[8 * ks + 2 * w2]), "v"(p[8 * ks + 2 * w2 + 1]));
          pw[w2] = pk_;
        }
        short8 pb = __builtin_bit_cast(short8, pw);
        int sl = ((2 * ks + hi) ^ r7) * 16;
        __builtin_amdgcn_s_setprio(1);
#pragma unroll
        for (int dt = 0; dt < 4; dt++) {
          short8 vf = *(const short8*)(Vb + dt * 32 * 128 + sl);
          accO[dt] = __builtin_amdgcn_mfma_f32_32x32x16_bf16(vf, pb, accO[dt], 0, 0, 0);
        }
        __builtin_amdgcn_s_setprio(0);
      }
    }

    // ---- combine even/odd partials (fixed max -> merge is a plain sum) ----
    __syncthreads();                                  // all compute done (cross-group)
    float* SM_acc = (float*)(SMEM + 32768);           // 64KB staging (dead post-compute)
    float* SM_l   = (float*)SMEM;                     // 512B (dead post-compute)
    const int q_local = wq * 32 + l31;
    if (g == 1) {
#pragma unroll
      for (int dt = 0; dt < 4; dt++)
#pragma unroll
        for (int r = 0; r < 16; r++) {
          int d = 32 * dt + (r & 3) + 8 * (r >> 2) + 4 * hi;
          SM_acc[q_local * 128 + (d ^ l31)] = accO[dt][r];   // word-swz: conflict-free
        }
      if (hi == 0) SM_l[q_local] = l_r;
    }
    __syncthreads();                                  // partials visible
    if (g == 0) {
      float lo = SM_l[q_local];
      float inv = 1.0f / (l_r + lo);                  // l_r > 0 (diagonal in even group)
#pragma unroll
      for (int dt = 0; dt < 4; dt++)
#pragma unroll
        for (int q4 = 0; q4 < 4; q4++) {
          int dbase = 32 * dt + 8 * q4 + 4 * hi;
          u16x4 o;
#pragma unroll
          for (int j = 0; j < 4; j++) {
            int r = q4 * 4 + j, d = dbase + j;
            float vo = SM_acc[q_local * 128 + (d ^ l31)];
            o[j] = f2bf((accO[dt][r] + vo) * inv);
          }
          *(u16x4*)(ao + (size_t)q_row * HDIM + h * HD + dbase) = o;
        }
    }
  }
}

// ---------------- launch ----------------
extern "C" void kernel_launch(void* const* d_in, const int* in_sizes, int n_in,
                              void* d_out, int out_size, void* d_ws, size_t ws_size,
                              hipStream_t stream) {
  const float* x      = (const float*)d_in[0];
  const float* ve     = (const float*)d_in[1];
  const float* lam    = (const float*)d_in[2];
  const float* qkv_w  = (const float*)d_in[3];
  const float* proj_w = (const float*)d_in[4];
  float* out = (float*)d_out;

  char* p = (char*)d_ws;
  float* cosT = (float*)p;            p += (size_t)T_SEQ * 64 * 4;
  float* sinT = (float*)p;            p += (size_t)T_SEQ * 64 * 4;
  unsigned short* xb   = (unsigned short*)p; p += (size_t)T_SEQ * DIM * 2;
  unsigned short* wqb  = (unsigned short*)p; p += (size_t)3 * HDIM * DIM * 2;
  unsigned short* pwb  = (unsigned short*)p; p += (size_t)DIM * HDIM * 2;
  unsigned short* qkvb = (unsigned short*)p; p += (size_t)3 * NH * T_SEQ * HD * 2;
  unsigned short* vtb  = (unsigned short*)p; p += (size_t)NH * HD * T_SEQ * 2;
  unsigned short* aob  = (unsigned short*)p; p += (size_t)T_SEQ * HDIM * 2;
  unsigned char*  qk8  = (unsigned char*)p;  p += (size_t)2 * NH * T_SEQ * HD;

  // fused prep: x/qkv_w/proj_w converts + rope tables (boundaries 256-aligned)
  constexpr int PREP_N = T_SEQ * DIM / 4 + 3 * HDIM * DIM / 4 + DIM * HDIM / 4 + T_SEQ * 64;
  prep_all<<<PREP_N / 256, 256, 0, stream>>>(x, qkv_w, proj_w, xb, wqb, pwb, cosT, sinT);

  // QKV: 768 blocks = 3/CU exactly (R16 barrier-minimal BK=64 kernel)
  gemm256<0><<<768, 512, 0, stream>>>(xb, wqb, DIM, qkvb, nullptr, 3 * HDIM);
  // fused norm+rope->fp8 (8192 blocks) + vmix-transpose (2048 blocks)
  norm_vmix<<<10240, 256, 0, stream>>>(qkvb, cosT, sinT, ve, lam, vtb, qk8);
  attn_fwd<<<256, 512, 0, stream>>>(qk8, qk8 + (size_t)NH * T_SEQ * HD, vtb, aob);
  // proj: 256 blocks = 1/CU exactly
  gemm256<1><<<256, 512, 0, stream>>>(aob, pwb, HDIM, nullptr, out, HDIM);
}

// Round 25
// 272.589 us; speedup vs baseline: 1.0329x; 1.0329x over previous
//
#include <hip/hip_runtime.h>
#include <cstdint>
#include <cstddef>

// ---------------- constants ----------------
constexpr int T_SEQ = 4096;
constexpr int NH    = 16;
constexpr int HD    = 128;
constexpr int DIM   = 2048;
constexpr int HDIM  = 2048;   // NH*HD

typedef __attribute__((ext_vector_type(8)))  short  short8;
typedef __attribute__((ext_vector_type(4)))  float  f32x4;
typedef __attribute__((ext_vector_type(16))) float  f32x16;
typedef __attribute__((ext_vector_type(8)))  unsigned short u16x8;
typedef __attribute__((ext_vector_type(4)))  unsigned short u16x4;
typedef __attribute__((ext_vector_type(4)))  unsigned uint4v;
typedef __attribute__((ext_vector_type(2)))  int int2v;

__device__ __forceinline__ unsigned short f2bf(float f) {
  unsigned u = __float_as_uint(f);
  return (unsigned short)((u + 0x7FFFu + ((u >> 16) & 1u)) >> 16);  // RNE
}
__device__ __forceinline__ float bf2f(unsigned short h) {
  return __uint_as_float(((unsigned)h) << 16);
}
__device__ __forceinline__ void gload_lds16(const void* g, void* l) {
  __builtin_amdgcn_global_load_lds((const __attribute__((address_space(1))) void*)g,
                                   (__attribute__((address_space(3))) void*)l, 16, 0, 0);
}
__device__ __forceinline__ int2v plswap(int a, int b) {
  return __builtin_amdgcn_permlane32_swap(a, b, false, false);
}
__device__ __forceinline__ void bar() {           // raw barrier: no implicit vmcnt(0)
  asm volatile("" ::: "memory");
  __builtin_amdgcn_s_barrier();
  asm volatile("" ::: "memory");
}
#define VMCNT(n) asm volatile("s_waitcnt vmcnt(" #n ")" ::: "memory")

// ---------------- fused prep: 3x fp32->bf16 convert + RoPE tables, one launch ----------
__global__ __launch_bounds__(256) void prep_all(const float* __restrict__ x,
                                                const float* __restrict__ qkv_w,
                                                const float* __restrict__ proj_w,
                                                unsigned short* __restrict__ xb,
                                                unsigned short* __restrict__ wqb,
                                                unsigned short* __restrict__ pwb,
                                                float* __restrict__ cosT,
                                                float* __restrict__ sinT) {
  constexpr int N1 = T_SEQ * DIM / 4;              // 2,097,152
  constexpr int N2 = N1 + 3 * HDIM * DIM / 4;      // +3,145,728
  constexpr int N3 = N2 + DIM * HDIM / 4;          // +1,048,576
  int gid = blockIdx.x * 256 + threadIdx.x;
  const float* src; unsigned short* dst; int i4;
  if (gid < N1)      { src = x;      dst = xb;  i4 = gid; }
  else if (gid < N2) { src = qkv_w;  dst = wqb; i4 = gid - N1; }
  else if (gid < N3) { src = proj_w; dst = pwb; i4 = gid - N2; }
  else {
    int idx = gid - N3;                            // T_SEQ*64 entries
    int t = idx >> 6, i = idx & 63;
    float ang = (i < 32) ? exp2f(-10.0f * (float)i / 31.0f) : 0.0f;  // (1/1024)^(i/31)
    float th = (float)t * ang;
    cosT[idx] = cosf(th);
    sinT[idx] = sinf(th);
    return;
  }
  float4 v = ((const float4*)src)[i4];
  u16x4 o; o.x = f2bf(v.x); o.y = f2bf(v.y); o.z = f2bf(v.z); o.w = f2bf(v.w);
  ((u16x4*)dst)[i4] = o;
}

// ---------------- QKV GEMM + FUSED RMSNorm/RoPE/fp8 epilogue ----------------
// K-loop: R16 barrier-minimal structure (proven best). Epilogue: a block's 128x256
// output tile covers exactly 2 complete heads of one c in {q,k,v} (n0 % 256 == 0,
// 2048 % 256 == 0). For q/k blocks: stage acc f32 -> LDS TL[128][260] (stride 260:
// write-phase bank aliasing is exactly 2-way = free), then run the proven norm/rope/
// fp8 row pipeline (16 lanes/row) straight from f32 -> qk8. Kills the q/k bf16
// HBM round-trip and one kernel boundary; norm on f32 is strictly MORE accurate.
// v blocks: plain bf16 write to vb[h][t][d] (vmix stays standalone).
__global__ __launch_bounds__(512) void gemm_qkv(const unsigned short* __restrict__ A,
                                                const unsigned short* __restrict__ B,
                                                const float* __restrict__ cosT,
                                                const float* __restrict__ sinT,
                                                unsigned char* __restrict__ qk8,
                                                unsigned short* __restrict__ vb) {
  __shared__ __align__(16) char SM[3 * 49152];   // 144KB: 3 x [A 16KB | B 32KB]
  const int tid = threadIdx.x, w = tid >> 6, lane = tid & 63;
  const int wm = w >> 2, wn = w & 3;
  const int lr = lane >> 4, lc = lane & 15, lc7 = lc & 7;
  const int cpx = gridDim.x >> 3;
  const int idx = (blockIdx.x & 7) * cpx + (blockIdx.x >> 3);
  const int m0 = (idx & 31) * 128, n0 = (idx >> 5) * 256;
  constexpr int K = DIM;

  const int arow = lane >> 3;
  const int xcol = ((lane & 7) ^ ((lane >> 3) & 7)) * 8;  // pre-swizzled source col

  auto stageA = [&](int buf, int t) {
    char* base = SM + buf * 49152;
#pragma unroll
    for (int i = 0; i < 2; i++) {
      int c = w + i * 8;
      gload_lds16(A + (size_t)(m0 + c * 8 + arow) * K + t * 64 + xcol, base + c * 1024);
    }
  };
  auto stageB0 = [&](int buf, int t) {
    char* base = SM + buf * 49152 + 16384;
    gload_lds16(B + (size_t)(n0 + w * 8 + arow) * K + t * 64 + xcol, base + w * 1024);
  };
  auto stageB1 = [&](int buf, int t) {
    char* base = SM + buf * 49152 + 16384;
#pragma unroll
    for (int i = 1; i < 4; i++) {
      int c = w + i * 8;
      gload_lds16(B + (size_t)(n0 + c * 8 + arow) * K + t * 64 + xcol, base + c * 1024);
    }
  };

  f32x4 acc[4][4] = {};
  const int NT = K >> 6;

  stageA(0, 0); stageB0(0, 0); stageB1(0, 0);
  stageA(1, 1); stageB0(1, 1); stageB1(1, 1);
  VMCNT(6);
  bar();

#pragma unroll 1
  for (int t = 0; t < NT; t++) {
    const int c = t % 3, s = (t + 2) % 3;
    const bool st = (t + 2) < NT;
    const char* Ab = SM + c * 49152;
    const char* Bb = Ab + 16384;

    short8 a[4], b[4];
#pragma unroll
    for (int mi = 0; mi < 4; mi++)
      a[mi] = *(const short8*)(Ab + (wm * 64 + mi * 16 + lc) * 128 + ((0 + lr) ^ lc7) * 16);
#pragma unroll
    for (int ni = 0; ni < 4; ni++)
      b[ni] = *(const short8*)(Bb + (wn * 64 + ni * 16 + lc) * 128 + ((0 + lr) ^ lc7) * 16);
    if (st) { stageA(s, t + 2); stageB0(s, t + 2); }
    __builtin_amdgcn_s_setprio(1);
#pragma unroll
    for (int mi = 0; mi < 4; mi++)
#pragma unroll
      for (int ni = 0; ni < 4; ni++)
        acc[mi][ni] = __builtin_amdgcn_mfma_f32_16x16x32_bf16(a[mi], b[ni], acc[mi][ni], 0, 0, 0);
    __builtin_amdgcn_s_setprio(0);

#pragma unroll
    for (int mi = 0; mi < 4; mi++)
      a[mi] = *(const short8*)(Ab + (wm * 64 + mi * 16 + lc) * 128 + ((4 + lr) ^ lc7) * 16);
#pragma unroll
    for (int ni = 0; ni < 4; ni++)
      b[ni] = *(const short8*)(Bb + (wn * 64 + ni * 16 + lc) * 128 + ((4 + lr) ^ lc7) * 16);
    if (st) stageB1(s, t + 2);
    if (st) { VMCNT(6); } else { VMCNT(0); }   // confirm tile t+1 (tail: drain)
    bar();                                     // (a) all waves' t+1 staging landed
    __builtin_amdgcn_s_setprio(1);
#pragma unroll
    for (int mi = 0; mi < 4; mi++)
#pragma unroll
      for (int ni = 0; ni < 4; ni++)
        acc[mi][ni] = __builtin_amdgcn_mfma_f32_16x16x32_bf16(a[mi], b[ni], acc[mi][ni], 0, 0, 0);
    __builtin_amdgcn_s_setprio(0);
    bar();                                     // (b) protect buf c vs t+1's stage
  }

  const int cc = n0 >> 11;                     // 0=q, 1=k, 2=v
  if (cc < 2) {
    // ---- fused epilogue: acc -> TL (f32) -> RMSNorm+RoPE -> fp8 qk8 ----
    float* TL = (float*)SM;                    // [128][260] (133KB <= 144KB)
#pragma unroll
    for (int mi = 0; mi < 4; mi++)
#pragma unroll
      for (int ni = 0; ni < 4; ni++)
#pragma unroll
        for (int r = 0; r < 4; r++)
          TL[(wm * 64 + mi * 16 + lr * 4 + r) * 260 + wn * 64 + ni * 16 + lc] =
              acc[mi][ni][r];
    bar();                                     // TL complete (all reads drained pre-bar)

    const int h0 = (n0 & 2047) >> 7;
    const int li = tid & 15, grp = tid >> 4;   // 16 lanes/row, 32 rows/iter
    const bool hi8 = li >= 8;
    const int e0 = (li & 7) * 8;
#pragma unroll 1
    for (int itr = 0; itr < 8; itr++) {
      int rr = itr * 32 + grp;                 // 0..255 = 128 t x 2 heads
      int hh = rr >> 7, tl2 = rr & 127;
      int tg = m0 + tl2;
      const float* rowp = TL + tl2 * 260 + hh * 128;
      f32x4 a4 = *(const f32x4*)(rowp + li * 8);
      f32x4 b4 = *(const f32x4*)(rowp + li * 8 + 4);
      float v[8];
#pragma unroll
      for (int j = 0; j < 4; j++) { v[j] = a4[j]; v[4 + j] = b4[j]; }
      float ss = 0.0f;
#pragma unroll
      for (int j = 0; j < 8; j++) ss += v[j] * v[j];
#pragma unroll
      for (int off = 1; off < 16; off <<= 1) ss += __shfl_xor(ss, off, 16);
      float rs = rsqrtf(ss * (1.0f / 128.0f) + 1e-6f);
      if (cc == 0) rs *= 0.088388347648318447f * 1.44269504f;  // q: fold scale*log2e

      float pv[8];
#pragma unroll
      for (int j = 0; j < 8; j++) pv[j] = __shfl_xor(v[j], 8, 16);  // rope partner d^64

      float4 c0 = *(const float4*)(cosT + tg * 64 + e0);
      float4 c1 = *(const float4*)(cosT + tg * 64 + e0 + 4);
      float4 s0 = *(const float4*)(sinT + tg * 64 + e0);
      float4 s1 = *(const float4*)(sinT + tg * 64 + e0 + 4);
      float ct[8] = {c0.x, c0.y, c0.z, c0.w, c1.x, c1.y, c1.z, c1.w};
      float sn[8] = {s0.x, s0.y, s0.z, s0.w, s1.x, s1.y, s1.z, s1.w};

      float rr8[8];
#pragma unroll
      for (int j = 0; j < 8; j++) {
        float x1 = hi8 ? pv[j] : v[j];
        float x2 = hi8 ? v[j] : pv[j];
        float r = hi8 ? (-x1 * sn[j] + x2 * ct[j]) : (x1 * ct[j] + x2 * sn[j]);
        rr8[j] = r * rs;
      }
      int w0 = 0, w1 = 0;
      w0 = __builtin_amdgcn_cvt_pk_fp8_f32(rr8[0], rr8[1], w0, false);
      w0 = __builtin_amdgcn_cvt_pk_fp8_f32(rr8[2], rr8[3], w0, true);
      w1 = __builtin_amdgcn_cvt_pk_fp8_f32(rr8[4], rr8[5], w1, false);
      w1 = __builtin_amdgcn_cvt_pk_fp8_f32(rr8[6], rr8[7], w1, true);
      int2v o8; o8.x = w0; o8.y = w1;
      *(int2v*)(qk8 + ((size_t)(cc * NH + h0 + hh) * T_SEQ + tg) * HD + li * 8) = o8;
    }
  } else {
    // ---- v blocks: plain bf16 write to vb[h][t][d] ----
#pragma unroll
    for (int mi = 0; mi < 4; mi++)
#pragma unroll
      for (int ni = 0; ni < 4; ni++)
#pragma unroll
        for (int r = 0; r < 4; r++) {
          int t = m0 + wm * 64 + mi * 16 + lr * 4 + r;
          int n = n0 + wn * 64 + ni * 16 + lc;
          int e = n & 2047, h = e >> 7, d = e & 127;
          vb[((size_t)h * T_SEQ + t) * HD + d] = f2bf(acc[mi][ni][r]);
        }
  }
}

// ---------------- proj GEMM (R16 barrier-minimal, fp32 out) ----------------
__global__ __launch_bounds__(512) void gemm256(const unsigned short* __restrict__ A,
                                               const unsigned short* __restrict__ B,
                                               int K, float* __restrict__ outf, int N) {
  __shared__ __align__(16) char SM[3 * 49152];   // 144KB: 3 x [A 16KB | B 32KB]
  const int tid = threadIdx.x, w = tid >> 6, lane = tid & 63;
  const int wm = w >> 2, wn = w & 3;
  const int lr = lane >> 4, lc = lane & 15, lc7 = lc & 7;
  const int cpx = gridDim.x >> 3;
  const int idx = (blockIdx.x & 7) * cpx + (blockIdx.x >> 3);
  const int m0 = (idx & 31) * 128, n0 = (idx >> 5) * 256;

  const int arow = lane >> 3;
  const int xcol = ((lane & 7) ^ ((lane >> 3) & 7)) * 8;  // pre-swizzled source col

  auto stageA = [&](int buf, int t) {
    char* base = SM + buf * 49152;
#pragma unroll
    for (int i = 0; i < 2; i++) {
      int c = w + i * 8;
      gload_lds16(A + (size_t)(m0 + c * 8 + arow) * K + t * 64 + xcol, base + c * 1024);
    }
  };
  auto stageB0 = [&](int buf, int t) {
    char* base = SM + buf * 49152 + 16384;
    gload_lds16(B + (size_t)(n0 + w * 8 + arow) * K + t * 64 + xcol, base + w * 1024);
  };
  auto stageB1 = [&](int buf, int t) {
    char* base = SM + buf * 49152 + 16384;
#pragma unroll
    for (int i = 1; i < 4; i++) {
      int c = w + i * 8;
      gload_lds16(B + (size_t)(n0 + c * 8 + arow) * K + t * 64 + xcol, base + c * 1024);
    }
  };

  f32x4 acc[4][4] = {};
  const int NT = K >> 6;

  stageA(0, 0); stageB0(0, 0); stageB1(0, 0);
  stageA(1, 1); stageB0(1, 1); stageB1(1, 1);
  VMCNT(6);
  bar();

#pragma unroll 1
  for (int t = 0; t < NT; t++) {
    const int c = t % 3, s = (t + 2) % 3;
    const bool st = (t + 2) < NT;
    const char* Ab = SM + c * 49152;
    const char* Bb = Ab + 16384;

    short8 a[4], b[4];
#pragma unroll
    for (int mi = 0; mi < 4; mi++)
      a[mi] = *(const short8*)(Ab + (wm * 64 + mi * 16 + lc) * 128 + ((0 + lr) ^ lc7) * 16);
#pragma unroll
    for (int ni = 0; ni < 4; ni++)
      b[ni] = *(const short8*)(Bb + (wn * 64 + ni * 16 + lc) * 128 + ((0 + lr) ^ lc7) * 16);
    if (st) { stageA(s, t + 2); stageB0(s, t + 2); }
    __builtin_amdgcn_s_setprio(1);
#pragma unroll
    for (int mi = 0; mi < 4; mi++)
#pragma unroll
      for (int ni = 0; ni < 4; ni++)
        acc[mi][ni] = __builtin_amdgcn_mfma_f32_16x16x32_bf16(a[mi], b[ni], acc[mi][ni], 0, 0, 0);
    __builtin_amdgcn_s_setprio(0);

#pragma unroll
    for (int mi = 0; mi < 4; mi++)
      a[mi] = *(const short8*)(Ab + (wm * 64 + mi * 16 + lc) * 128 + ((4 + lr) ^ lc7) * 16);
#pragma unroll
    for (int ni = 0; ni < 4; ni++)
      b[ni] = *(const short8*)(Bb + (wn * 64 + ni * 16 + lc) * 128 + ((4 + lr) ^ lc7) * 16);
    if (st) stageB1(s, t + 2);
    if (st) { VMCNT(6); } else { VMCNT(0); }   // confirm tile t+1 (tail: drain)
    bar();                                     // (a) all waves' t+1 staging landed
    __builtin_amdgcn_s_setprio(1);
#pragma unroll
    for (int mi = 0; mi < 4; mi++)
#pragma unroll
      for (int ni = 0; ni < 4; ni++)
        acc[mi][ni] = __builtin_amdgcn_mfma_f32_16x16x32_bf16(a[mi], b[ni], acc[mi][ni], 0, 0, 0);
    __builtin_amdgcn_s_setprio(0);
    bar();                                     // (b) protect buf c vs t+1's stage
  }

#pragma unroll
  for (int mi = 0; mi < 4; mi++)
#pragma unroll
    for (int ni = 0; ni < 4; ni++)
#pragma unroll
      for (int r = 0; r < 4; r++) {
        int t = m0 + wm * 64 + mi * 16 + lr * 4 + r;
        int n = n0 + wn * 64 + ni * 16 + lc;
        outf[(size_t)t * N + n] = acc[mi][ni][r];
      }
}

// ---------------- vmix-transpose: v' = l0*v + l1*ve -> vt[h][d][t] ----------------
__global__ __launch_bounds__(256) void vmix_transpose(const unsigned short* __restrict__ vb,
                                                      const float* __restrict__ ve,
                                                      const float* __restrict__ lam,
                                                      unsigned short* __restrict__ vt) {
  __shared__ float tile[64][65];
  const int tid = threadIdx.x;
  const int j2 = blockIdx.x;                      // 0..2047
  const int t0 = (j2 & 63) * 64, d0 = ((j2 >> 6) & 1) * 64, h = j2 >> 7;
  const float l0 = lam[0], l1 = lam[1];
  const int tl = tid >> 4, dl4 = (tid & 15) * 4;
#pragma unroll
  for (int i = 0; i < 4; i++) {
    int t_local = tl + i * 16;
    int t = t0 + t_local;
    const unsigned short* vp = vb + ((size_t)h * T_SEQ + t) * HD + d0 + dl4;
    const float* vep = ve + (size_t)t * HDIM + h * HD + d0 + dl4;
    u16x4 vv = *(const u16x4*)vp;
    float4 vef = *(const float4*)vep;
    tile[t_local][dl4 + 0] = l0 * bf2f(vv.x) + l1 * vef.x;
    tile[t_local][dl4 + 1] = l0 * bf2f(vv.y) + l1 * vef.y;
    tile[t_local][dl4 + 2] = l0 * bf2f(vv.z) + l1 * vef.z;
    tile[t_local][dl4 + 3] = l0 * bf2f(vv.w) + l1 * vef.w;
  }
  __syncthreads();
#pragma unroll
  for (int i = 0; i < 2; i++) {
    int idx = tid + i * 256;
    int d_local = idx >> 3, tloc = (idx & 7) * 8;
    u16x8 o;
#pragma unroll
    for (int j = 0; j < 8; j++) o[j] = f2bf(tile[tloc + j][d_local]);
    *(u16x8*)(vt + ((size_t)h * HD + d0 + d_local) * T_SEQ + t0 + tloc) = o;
  }
}

// ---------------- flash attention (causal): FP8 QK^T + bf16 PV, 32x32x16 ----------------
// R20/R22 best measured (118us): fp8 QK (K LDS tile 8KB), FM=18.75, sigma K-row
// permutation (lane-local PV), kv-parity group split with drift barriers, double-
// buffered K+V, bf16 output.
__global__ __launch_bounds__(512)
__attribute__((amdgpu_waves_per_eu(2, 2)))
void attn_fwd(const unsigned char* __restrict__ q8,
              const unsigned char* __restrict__ k8,
              const unsigned short* __restrict__ vt,
              unsigned short* __restrict__ ao) {
  __shared__ __align__(16) char SMEM[98304];    // [group][ K 2x8KB | V 2x16KB ]
  __shared__ int gctr[2];                       // group-barrier monotonic counters
  const int bid = blockIdx.x;
  const int h  = (bid & 7) + ((bid >> 7) << 3);  // XCD swizzle: head h on XCD h%8
  const int pr = (bid >> 3) & 15;
  const int tid = threadIdx.x, w = tid >> 6, lane = tid & 63;
  const int g = w >> 2, wq = w & 3;
  const int l31 = lane & 31, hi = lane >> 5, r7 = l31 & 7;
  const unsigned char* qh = q8 + (size_t)h * T_SEQ * HD;
  const unsigned char* kh = k8 + (size_t)h * T_SEQ * HD;
  const unsigned short* vh = vt + (size_t)h * HD * T_SEQ;

  if (tid < 2) gctr[tid] = 0;
  __syncthreads();
  int bcnt = 0;
  auto GBAR = [&]() {   // group-local barrier: 4 waves of group g
    asm volatile("s_waitcnt lgkmcnt(0)" ::: "memory");
    ++bcnt;
    if (lane == 0)
      __hip_atomic_fetch_add(&gctr[g], 1, __ATOMIC_RELEASE, __HIP_MEMORY_SCOPE_WORKGROUP);
    while (__hip_atomic_load(&gctr[g], __ATOMIC_ACQUIRE, __HIP_MEMORY_SCOPE_WORKGROUP) < 4 * bcnt)
      __builtin_amdgcn_s_sleep(1);
  };

  char* Kbase = SMEM + g * 49152;               // 2 x 8KB
  char* Vbase = Kbase + 16384;                  // 2 x 16KB

  const int vcrow = lane >> 3, vslot0 = lane & 7;    // V staging: 8 rows / 1KB chunk

  auto STAGE = [&](int buf, int t) {                 // t = global kv tile index
#pragma unroll
    for (int i = 0; i < 2; i++) {
      int c = wq * 2 + i;
      int r = c * 8 + (lane >> 3);                   // LDS row position
      int rsrc = (r & ~12) | ((r & 4) << 1) | ((r & 8) >> 1);  // sigma: b2<->b3
      int sl = ((lane & 7) ^ (r & 7)) * 16;          // pre-swizzled source slot
      gload_lds16(kh + (size_t)(t * 64 + rsrc) * HD + sl,
                  Kbase + buf * 8192 + c * 1024);
    }
#pragma unroll
    for (int i = 0; i < 4; i++) {
      int vrow = (wq * 4 + i) * 8 + vcrow;
      int vcol = (vslot0 ^ (vrow & 7)) * 8;
      gload_lds16(vh + (size_t)vrow * T_SEQ + t * 64 + vcol,
                  Vbase + buf * 16384 + (wq * 4 + i) * 1024);
    }
  };

  const float FM = 18.75f;   // fixed softmax max (exp2 domain) incl. fp8 norm inflation

#pragma unroll 1
  for (int which = 0; which < 2; ++which) {
    const int qt = which ? pr : (31 - pr);     // heavy tile first
    const int ng = qt + 1;                     // tiles for THIS group (parity g)
    const int q_row = qt * 128 + wq * 32 + l31;

    long qf8[8];                               // B-frag: Q[q_row][16dk + 8hi + 0..7] fp8
#pragma unroll
    for (int dk = 0; dk < 8; dk++)
      qf8[dk] = *(const long*)(qh + (size_t)q_row * HD + dk * 16 + hi * 8);

    f32x16 accO[4] = {};                       // O^T: col=q, rows d (4 tiles of 32)
    float l_r = 0.0f;

    __syncthreads();                           // prev combine reads done (cross-group)
    STAGE(0, g);

#pragma unroll 1
    for (int it = 0; it < ng; it++) {
      const int t = 2 * it + g;                // this group's kv tile
      const int cur = it & 1;
      asm volatile("s_waitcnt vmcnt(0)" ::: "memory");  // own stage(cur) landed
      GBAR();                                           // group's stage(cur) landed
      if (it + 1 < ng) STAGE(cur ^ 1, t + 2);           // prefetch under compute

      // ---- S^T = K Q^T : 2 kv-subtiles x 8 d-steps (fp8 x fp8 -> f32) ----
      f32x16 accS0 = {}, accS1 = {};
      const char* Kb = Kbase + cur * 8192;
      __builtin_amdgcn_s_setprio(1);
#pragma unroll
      for (int dk = 0; dk < 8; dk++) {
        int off = l31 * 128 + ((dk ^ r7) * 16) + hi * 8;
        long k0 = *(const long*)(Kb + off);
        long k1 = *(const long*)(Kb + 32 * 128 + off);
        accS0 = __builtin_amdgcn_mfma_f32_32x32x16_fp8_fp8(k0, qf8[dk], accS0, 0, 0, 0);
        accS1 = __builtin_amdgcn_mfma_f32_32x32x16_fp8_fp8(k1, qf8[dk], accS1, 0, 0, 0);
      }
      __builtin_amdgcn_s_setprio(0);

      // ---- causal mask + exp2(s - FM); permuted layout: kv = 64t+(r&7)+8hi+16(r>>3) ----
      float p[32];
      const bool need_mask = (t * 64 + 63) > (qt * 128 + wq * 32);
      if (need_mask) {
#pragma unroll
        for (int r = 0; r < 16; r++) {
          int kv0 = t * 64 + (r & 7) + 8 * hi + 16 * (r >> 3);
          p[r]      = (kv0      > q_row) ? 0.0f : exp2f(accS0[r] - FM);
          p[16 + r] = (kv0 + 32 > q_row) ? 0.0f : exp2f(accS1[r] - FM);
        }
      } else {
#pragma unroll
        for (int r = 0; r < 16; r++) {
          p[r]      = exp2f(accS0[r] - FM);
          p[16 + r] = exp2f(accS1[r] - FM);
        }
      }

      // ---- row sum (partner holds complementary kv set; one cross-half swap) ----
      float s16[16];
#pragma unroll
      for (int i = 0; i < 16; i++) s16[i] = p[i] + p[i + 16];
#pragma unroll
      for (int st = 8; st >= 1; st >>= 1)
#pragma unroll
        for (int i = 0; i < st; i++) s16[i] += s16[i + st];
      int2v sr_ = plswap(__float_as_int(s16[0]), __float_as_int(s16[0]));
      l_r += s16[0] + __int_as_float(hi ? sr_.x : sr_.y);

      // ---- PV: O^T += V^T P^T ; pb[ks] = p[8ks..8ks+7] (lane-local, no exchange) ----
      const char* Vb = Vbase + cur * 16384 + l31 * 128;
#pragma unroll
      for (int ks = 0; ks < 4; ks++) {
        uint4v pw;
#pragma unroll
        for (int w2 = 0; w2 < 4; w2++) {
          unsigned pk_;
          asm("v_cvt_pk_bf16_f32 %0, %1, %2"
              : "=v"(pk_) : "v"(p[8 * ks + 2 * w2]), "v"(p[8 * ks + 2 * w2 + 1]));
          pw[w2] = pk_;
        }
        short8 pb = __builtin_bit_cast(short8, pw);
        int sl = ((2 * ks + hi) ^ r7) * 16;
        __builtin_amdgcn_s_setprio(1);
#pragma unroll
        for (int dt = 0; dt < 4; dt++) {
          short8 vf = *(const short8*)(Vb + dt * 32 * 128 + sl);
          accO[dt] = __builtin_amdgcn_mfma_f32_32x32x16_bf16(vf, pb, accO[dt], 0, 0, 0);
        }
        __builtin_amdgcn_s_setprio(0);
      }
    }

    // ---- combine even/odd partials (fixed max -> merge is a plain sum) ----
    __syncthreads();                                  // all compute done (cross-group)
    float* SM_acc = (float*)(SMEM + 32768);           // 64KB staging (dead post-compute)
    float* SM_l   = (float*)SMEM;                     // 512B (dead post-compute)
    const int q_local = wq * 32 + l31;
    if (g == 1) {
#pragma unroll
      for (int dt = 0; dt < 4; dt++)
#pragma unroll
        for (int r = 0; r < 16; r++) {
          int d = 32 * dt + (r & 3) + 8 * (r >> 2) + 4 * hi;
          SM_acc[q_local * 128 + (d ^ l31)] = accO[dt][r];   // word-swz: conflict-free
        }
      if (hi == 0) SM_l[q_local] = l_r;
    }
    __syncthreads();                                  // partials visible
    if (g == 0) {
      float lo = SM_l[q_local];
      float inv = 1.0f / (l_r + lo);                  // l_r > 0 (diagonal in even group)
#pragma unroll
      for (int dt = 0; dt < 4; dt++)
#pragma unroll
        for (int q4 = 0; q4 < 4; q4++) {
          int dbase = 32 * dt + 8 * q4 + 4 * hi;
          u16x4 o;
#pragma unroll
          for (int j = 0; j < 4; j++) {
            int r = q4 * 4 + j, d = dbase + j;
            float vo = SM_acc[q_local * 128 + (d ^ l31)];
            o[j] = f2bf((accO[dt][r] + vo) * inv);
          }
          *(u16x4*)(ao + (size_t)q_row * HDIM + h * HD + dbase) = o;
        }
    }
  }
}

// ---------------- launch ----------------
extern "C" void kernel_launch(void* const* d_in, const int* in_sizes, int n_in,
                              void* d_out, int out_size, void* d_ws, size_t ws_size,
                              hipStream_t stream) {
  const float* x      = (const float*)d_in[0];
  const float* ve     = (const float*)d_in[1];
  const float* lam    = (const float*)d_in[2];
  const float* qkv_w  = (const float*)d_in[3];
  const float* proj_w = (const float*)d_in[4];
  float* out = (float*)d_out;

  char* p = (char*)d_ws;
  float* cosT = (float*)p;            p += (size_t)T_SEQ * 64 * 4;
  float* sinT = (float*)p;            p += (size_t)T_SEQ * 64 * 4;
  unsigned short* xb   = (unsigned short*)p; p += (size_t)T_SEQ * DIM * 2;
  unsigned short* wqb  = (unsigned short*)p; p += (size_t)3 * HDIM * DIM * 2;
  unsigned short* pwb  = (unsigned short*)p; p += (size_t)DIM * HDIM * 2;
  unsigned short* vbuf = (unsigned short*)p; p += (size_t)NH * T_SEQ * HD * 2;
  unsigned short* vtb  = (unsigned short*)p; p += (size_t)NH * HD * T_SEQ * 2;
  unsigned short* aob  = (unsigned short*)p; p += (size_t)T_SEQ * HDIM * 2;
  unsigned char*  qk8  = (unsigned char*)p;  p += (size_t)2 * NH * T_SEQ * HD;

  // fused prep: x/qkv_w/proj_w converts + rope tables (boundaries 256-aligned)
  constexpr int PREP_N = T_SEQ * DIM / 4 + 3 * HDIM * DIM / 4 + DIM * HDIM / 4 + T_SEQ * 64;
  prep_all<<<PREP_N / 256, 256, 0, stream>>>(x, qkv_w, proj_w, xb, wqb, pwb, cosT, sinT);

  // QKV GEMM with fused norm/rope/fp8 epilogue (q,k -> qk8; v -> vbuf)
  gemm_qkv<<<768, 512, 0, stream>>>(xb, wqb, cosT, sinT, qk8, vbuf);
  // vmix-transpose (v only)
  vmix_transpose<<<2048, 256, 0, stream>>>(vbuf, ve, lam, vtb);
  attn_fwd<<<256, 512, 0, stream>>>(qk8, qk8 + (size_t)NH * T_SEQ * HD, vtb, aob);
  // proj: 256 blocks = 1/CU exactly
  gemm256<<<256, 512, 0, stream>>>(aob, pwb, HDIM, out, HDIM);
}